// Round 13
// baseline (145.632 us; speedup 1.0000x reference)
//
#include <hip/hip_runtime.h>
#include <hip/hip_bf16.h>

#define D 128  // D_IN == D_OUT == 128

typedef __attribute__((ext_vector_type(8))) short short8v;   // 8 bf16 (4 VGPR)
typedef __attribute__((ext_vector_type(4))) float float4v;   // MFMA acc

__device__ __forceinline__ unsigned short f2bf(float f) {
  union { float f; unsigned int u; } v; v.f = f;
  unsigned int r = v.u + 0x7fffu + ((v.u >> 16) & 1u);  // RNE
  return (unsigned short)(r >> 16);
}
__device__ __forceinline__ unsigned int pkbf(float lo, float hi) {
  float2 f; f.x = lo; f.y = hi;
  __hip_bfloat162 v = __float22bfloat162_rn(f);
  union { __hip_bfloat162 b; unsigned int u; } c; c.b = v;
  return c.u;
}
__device__ __forceinline__ float bflo(unsigned int u) {
  union { unsigned int v; float f; } c; c.v = u << 16; return c.f;
}
__device__ __forceinline__ float bfhi(unsigned int u) {
  union { unsigned int v; float f; } c; c.v = u & 0xffff0000u; return c.f;
}

// ==== prep: x_bf = bf16(nf); Wt = bf16(W^T); em_bf; sentinels; fused hist ==
// counts must be zeroed BEFORE this kernel (hipMemsetAsync) since hist
// atomics here race with any same-kernel zeroing.
__global__ __launch_bounds__(256) void prep_kernel(
    const float* __restrict__ nf, const float* __restrict__ W,
    const float* __restrict__ eemb, unsigned short* __restrict__ x_bf,
    unsigned short* __restrict__ Wt, unsigned short* __restrict__ em_bf,
    const int* __restrict__ eidx_tgt, int* __restrict__ counts,
    int n_nodes, int n_edges, int epb) {
  const int gid = blockIdx.x * 256 + threadIdx.x;
  const int stride = gridDim.x * 256;

  // ---- x cast: 8 floats -> 8 bf16 (uint4 store) per iteration ----
  const int total8 = n_nodes * (D / 8);  // 1.6M chunks
  const float4* nf4 = (const float4*)nf;
  uint4* xb4 = (uint4*)x_bf;
  for (int i = gid; i < total8; i += stride) {
    const float4 a = nf4[i * 2];
    const float4 c = nf4[i * 2 + 1];
    uint4 o;
    o.x = pkbf(a.x, a.y); o.y = pkbf(a.z, a.w);
    o.z = pkbf(c.x, c.y); o.w = pkbf(c.z, c.w);
    xb4[i] = o;
  }

  // ---- small tables ----
  if (gid < D * D) Wt[gid] = f2bf(W[(gid & 127) * D + (gid >> 7)]);
  if (gid < 64 * D) em_bf[gid] = f2bf(eemb[gid]);
  if (gid < 64) ((unsigned int*)(x_bf + (size_t)n_nodes * D))[gid] = 0u;
  if (gid >= 64 && gid < 128)
    ((unsigned int*)(em_bf + 64 * D))[gid - 64] = 0u;

  // ---- fused edge-target histogram chunk ----
  const int ebase = blockIdx.x * epb;
  int eend = ebase + epb;
  if (eend > n_edges) eend = n_edges;
  for (int e = ebase + threadIdx.x; e < eend; e += 256)
    atomicAdd(&counts[eidx_tgt[e]], 1);
}

// ============================ scan =========================================
__global__ __launch_bounds__(256) void scan1_kernel(
    const int* __restrict__ counts, int* __restrict__ offsets,
    int* __restrict__ blockSums, int n) {
  __shared__ int lds[256];
  const int tid = threadIdx.x;
  const int base = blockIdx.x * 1024 + tid * 4;
  int v[4];
  #pragma unroll
  for (int k = 0; k < 4; ++k) v[k] = (base + k < n) ? counts[base + k] : 0;
  int s = v[0] + v[1] + v[2] + v[3];
  lds[tid] = s;
  for (int off = 1; off < 256; off <<= 1) {
    __syncthreads();
    int t = (tid >= off) ? lds[tid - off] : 0;
    __syncthreads();
    lds[tid] += t;
  }
  __syncthreads();
  int run = lds[tid] - s;
  #pragma unroll
  for (int k = 0; k < 4; ++k) {
    if (base + k < n) offsets[base + k] = run;
    run += v[k];
  }
  if (tid == 255) blockSums[blockIdx.x] = lds[255];
}

__global__ __launch_bounds__(256) void scan23_kernel(
    int* __restrict__ offsets, int* __restrict__ cursor,
    const int* __restrict__ blockSums, int nb, int n, int n_edges) {
  __shared__ int lds[256];
  const int tid = threadIdx.x;
  const int bid = blockIdx.x;
  lds[tid] = (tid < bid && tid < nb) ? blockSums[tid] : 0;
  __syncthreads();
  #pragma unroll
  for (int off = 128; off > 0; off >>= 1) {
    if (tid < off) lds[tid] += lds[tid + off];
    __syncthreads();
  }
  const int add = lds[0];
  const int base = bid * 1024 + tid * 4;
  #pragma unroll
  for (int k = 0; k < 4; ++k) {
    int i = base + k;
    if (i < n) {
      int o = offsets[i] + add;
      offsets[i] = o;
      cursor[i] = o;
    }
  }
  if (bid == 0 && tid == 0) offsets[n] = n_edges;
}

// ================== scatter: 4 edges/thread via int4 =======================
__global__ __launch_bounds__(256) void scatter_kernel(
    const int* __restrict__ eidx, const int* __restrict__ etype,
    int* __restrict__ cursor, unsigned int* __restrict__ packed, int n_edges) {
  const int e0 = (blockIdx.x * 256 + threadIdx.x) * 4;
  if (e0 + 3 < n_edges) {
    const int4 s4 = *(const int4*)&eidx[e0];
    const int4 t4 = *(const int4*)&eidx[n_edges + e0];
    const int4 y4 = *(const int4*)&etype[e0];
    int pos;
    pos = atomicAdd(&cursor[t4.x], 1);
    packed[pos] = (unsigned int)s4.x | ((unsigned int)y4.x << 17);
    pos = atomicAdd(&cursor[t4.y], 1);
    packed[pos] = (unsigned int)s4.y | ((unsigned int)y4.y << 17);
    pos = atomicAdd(&cursor[t4.z], 1);
    packed[pos] = (unsigned int)s4.z | ((unsigned int)y4.z << 17);
    pos = atomicAdd(&cursor[t4.w], 1);
    packed[pos] = (unsigned int)s4.w | ((unsigned int)y4.w << 17);
  } else {
    for (int e = e0; e < n_edges; ++e) {
      const int pos = atomicAdd(&cursor[eidx[n_edges + e]], 1);
      packed[pos] = (unsigned int)eidx[e] | ((unsigned int)etype[e] << 17);
    }
  }
}

// ====== fused aggregate + GEMM + ReLU: one 512-thread block = 16 nodes =====
// out[n] = relu( (x[n] + Sum x[src]) @ W + (deg+1)*b + Sum emb[et] )
// Phase 1 (agg): 8 waves x 2 nodes each; lane = 4 dims via uint2 gathers of
//   x_bf (bf16 table) + em_bf; f32 accumulation; 4-deep pipeline.
// Phase 2 (gemm): stage sx (bf16, XOR-swizzled) + se + deg in LDS; wave w
//   computes out cols [w*16, w*16+16) x 16 nodes via 4 MFMAs (K=128).
__global__ __launch_bounds__(512) void agg_gemm_kernel(
    const int* __restrict__ offsets, const unsigned int* __restrict__ packed,
    const uint2* __restrict__ e4, const uint2* __restrict__ x4,
    const unsigned short* __restrict__ Wt, const float* __restrict__ b,
    float* __restrict__ out, int n_nodes, int n_edges, unsigned int zero_p) {
  __shared__ uint4 sx_l[16 * 16];  // 16 nodes x 128 bf16 (256B rows), 4 KB
  __shared__ uint4 se_l[16 * 16];  // same layout for edge-emb sums
  __shared__ float deg_l[16];

  const int tid = threadIdx.x;
  const int w = tid >> 6;          // wave 0..7
  const int ln = tid & 63;
  const int half = ln >> 5;
  const int sl = ln & 31;
  const int node16 = w * 2 + half;           // 0..15
  const int nodeBase = blockIdx.x * 16;
  const int n = nodeBase + node16;           // < n_nodes (100000 % 16 == 0)

  // ---------------- phase 1: aggregate ----------------
  const uint2 sb = x4[(size_t)n * 32 + sl];  // self (4 bf16)
  float a0 = bflo(sb.x), a1 = bfhi(sb.x), a2 = bflo(sb.y), a3 = bfhi(sb.y);
  float c0 = 0.f, c1 = 0.f, c2 = 0.f, c3 = 0.f;
  float s0 = 0.f, s1 = 0.f, s2 = 0.f, s3 = 0.f;   // emb sums
  float u0 = 0.f, u1 = 0.f, u2 = 0.f, u3 = 0.f;

  int j = offsets[n];
  const int end = offsets[n + 1];
  const float degp1 = (float)(end - j) + 1.0f;
  int trips = (end - j + 3) >> 2;
  int to = __shfl_xor(trips, 32);
  const int T = trips > to ? trips : to;
  const int emax = n_edges - 1;

  for (int t = 0; t < T; ++t, j += 4) {
    const int j1 = j + 1, j2 = j + 2, j3 = j + 3;
    unsigned int p0 = packed[j  <= emax ? j  : emax];
    unsigned int p1 = packed[j1 <= emax ? j1 : emax];
    unsigned int p2 = packed[j2 <= emax ? j2 : emax];
    unsigned int p3 = packed[j3 <= emax ? j3 : emax];
    p0 = (j  < end) ? p0 : zero_p;
    p1 = (j1 < end) ? p1 : zero_p;
    p2 = (j2 < end) ? p2 : zero_p;
    p3 = (j3 < end) ? p3 : zero_p;
    const uint2 g0 = x4[(size_t)(p0 & 0x1FFFFu) * 32 + sl];
    const uint2 g1 = x4[(size_t)(p1 & 0x1FFFFu) * 32 + sl];
    const uint2 g2 = x4[(size_t)(p2 & 0x1FFFFu) * 32 + sl];
    const uint2 g3 = x4[(size_t)(p3 & 0x1FFFFu) * 32 + sl];
    const uint2 e0 = e4[(p0 >> 17) * 32 + sl];
    const uint2 e1 = e4[(p1 >> 17) * 32 + sl];
    const uint2 e2 = e4[(p2 >> 17) * 32 + sl];
    const uint2 e3 = e4[(p3 >> 17) * 32 + sl];
    a0 += bflo(g0.x); a1 += bfhi(g0.x); a2 += bflo(g0.y); a3 += bfhi(g0.y);
    s0 += bflo(e0.x); s1 += bfhi(e0.x); s2 += bflo(e0.y); s3 += bfhi(e0.y);
    c0 += bflo(g1.x); c1 += bfhi(g1.x); c2 += bflo(g1.y); c3 += bfhi(g1.y);
    u0 += bflo(e1.x); u1 += bfhi(e1.x); u2 += bflo(e1.y); u3 += bfhi(e1.y);
    a0 += bflo(g2.x); a1 += bfhi(g2.x); a2 += bflo(g2.y); a3 += bfhi(g2.y);
    s0 += bflo(e2.x); s1 += bfhi(e2.x); s2 += bflo(e2.y); s3 += bfhi(e2.y);
    c0 += bflo(g3.x); c1 += bfhi(g3.x); c2 += bflo(g3.y); c3 += bfhi(g3.y);
    u0 += bflo(e3.x); u1 += bfhi(e3.x); u2 += bflo(e3.y); u3 += bfhi(e3.y);
  }

  // ---------------- stage to LDS (XOR-swizzled rows) ----------------
  {
    const int byte = (node16 * 256 + sl * 8) ^ ((node16 & 7) << 4);
    uint2 vx, ve;
    vx.x = pkbf(a0 + c0, a1 + c1);
    vx.y = pkbf(a2 + c2, a3 + c3);
    ve.x = pkbf(s0 + u0, s1 + u1);
    ve.y = pkbf(s2 + u2, s3 + u3);
    *(uint2*)((char*)sx_l + byte) = vx;
    *(uint2*)((char*)se_l + byte) = ve;
    if (sl == 0) deg_l[node16] = degp1;
  }
  __syncthreads();

  // ---------------- phase 2: 16-node x 128-col GEMM tile ----------------
  const int m = ln & 15;   // node (B col / D col)
  const int q = ln >> 4;   // k-quarter / D row-quarter

  float4v acc = {};
  #pragma unroll
  for (int kc = 0; kc < 4; ++kc) {
    const short8v av =
        *(const short8v*)&Wt[(w * 16 + m) * D + kc * 32 + q * 8];
    const int bbyte = (m * 256 + kc * 64 + q * 16) ^ ((m & 7) << 4);
    const short8v bv = *(const short8v*)((const char*)sx_l + bbyte);
    acc = __builtin_amdgcn_mfma_f32_16x16x32_bf16(av, bv, acc, 0, 0, 0);
  }

  // epilogue: + (deg+1)*b + se, ReLU, float4 store
  {
    const int col0 = w * 16 + q * 4;
    const float4 bv = *(const float4*)&b[col0];
    const int sbyte = (m * 256 + col0 * 2) ^ ((m & 7) << 4);
    const uint2 sev = *(const uint2*)((const char*)se_l + sbyte);
    const float dp1 = deg_l[m];
    float4 r;
    r.x = fmaxf(acc[0] + bv.x * dp1 + bflo(sev.x), 0.f);
    r.y = fmaxf(acc[1] + bv.y * dp1 + bfhi(sev.x), 0.f);
    r.z = fmaxf(acc[2] + bv.z * dp1 + bflo(sev.y), 0.f);
    r.w = fmaxf(acc[3] + bv.w * dp1 + bfhi(sev.y), 0.f);
    *(float4*)&out[(size_t)(nodeBase + m) * D + col0] = r;
  }
}

// ===========================================================================
extern "C" void kernel_launch(void* const* d_in, const int* in_sizes, int n_in,
                              void* d_out, int out_size, void* d_ws,
                              size_t ws_size, hipStream_t stream) {
  const float* nf   = (const float*)d_in[0];  // (N, 128) f32
  const int*   eidx = (const int*)d_in[1];    // (2, E) int
  const int*   etyp = (const int*)d_in[2];    // (E,) int
  const float* eemb = (const float*)d_in[3];  // (64, 128) f32
  const float* W    = (const float*)d_in[4];  // (128, 128) f32
  const float* b    = (const float*)d_in[5];  // (128,) f32

  const int n_nodes = in_sizes[0] / D;  // 100000
  const int n_edges = in_sizes[2];      // 625000

  float* out = (float*)d_out;

  // workspace layout (~29.5 MB); 16B alignment maintained
  char* base = (char*)d_ws;
  unsigned short* Wt = (unsigned short*)base;                  // 32 KB
  unsigned short* em_bf = (unsigned short*)(base + 32768);     // 65 rows
  unsigned short* x_bf = (unsigned short*)(base + 65536);      // (N+1)*128 bf16
  char* tail = base + 65536 + (size_t)(n_nodes + 1) * D * 2;
  int* counts = (int*)tail;
  int* offsets = counts + n_nodes;
  int* cursor = offsets + (n_nodes + 1);
  int* blockSums = cursor + n_nodes;
  unsigned int* packed = (unsigned int*)(blockSums + 1024);    // E uints

  const int nb = (n_nodes + 1023) / 1024;   // 98 scan blocks (<=256)
  const int prepBlocks = 2048;
  const int epb = (n_edges + prepBlocks - 1) / prepBlocks;  // ~306

  // 0) zero counts (must precede fused hist in prep)
  (void)hipMemsetAsync(counts, 0, (size_t)n_nodes * 4, stream);

  // 1) prep: x->bf16 cast, Wt/em tables, sentinels, fused histogram
  prep_kernel<<<prepBlocks, 256, 0, stream>>>(nf, W, eemb, x_bf, Wt, em_bf,
                                              eidx + n_edges, counts,
                                              n_nodes, n_edges, epb);

  // 2) scan (2 kernels)
  scan1_kernel<<<nb, 256, 0, stream>>>(counts, offsets, blockSums, n_nodes);
  scan23_kernel<<<nb, 256, 0, stream>>>(offsets, cursor, blockSums, nb,
                                        n_nodes, n_edges);

  // 3) scatter packed (src|etype) by target
  scatter_kernel<<<(n_edges + 1023) / 1024, 256, 0, stream>>>(
      eidx, etyp, cursor, packed, n_edges);

  // 4) fused aggregate + GEMM + ReLU (16 nodes / 512-thread block)
  const unsigned int zero_p = (unsigned int)n_nodes | (64u << 17);
  agg_gemm_kernel<<<n_nodes / 16, 512, 0, stream>>>(
      offsets, packed, (const uint2*)em_bf, (const uint2*)x_bf, Wt, b, out,
      n_nodes, n_edges, zero_p);
}

// Round 14
// 137.738 us; speedup vs baseline: 1.0573x; 1.0573x over previous
//
#include <hip/hip_runtime.h>
#include <hip/hip_bf16.h>

#define D 128  // D_IN == D_OUT == 128

typedef __attribute__((ext_vector_type(8))) short short8v;   // 8 bf16 (4 VGPR)
typedef __attribute__((ext_vector_type(4))) float float4v;   // MFMA acc

__device__ __forceinline__ unsigned short f2bf(float f) {
  union { float f; unsigned int u; } v; v.f = f;
  unsigned int r = v.u + 0x7fffu + ((v.u >> 16) & 1u);  // RNE
  return (unsigned short)(r >> 16);
}
__device__ __forceinline__ unsigned int pkbf(float lo, float hi) {
  float2 f; f.x = lo; f.y = hi;
  __hip_bfloat162 v = __float22bfloat162_rn(f);
  union { __hip_bfloat162 b; unsigned int u; } c; c.b = v;
  return c.u;
}
__device__ __forceinline__ float bflo(unsigned int u) {
  union { unsigned int v; float f; } c; c.v = u << 16; return c.f;
}
__device__ __forceinline__ float bfhi(unsigned int u) {
  union { unsigned int v; float f; } c; c.v = u & 0xffff0000u; return c.f;
}

// ==== prep: x_bf = bf16(nf); Wt = bf16(W^T); em_bf; sentinels; fused hist ==
__global__ __launch_bounds__(256) void prep_kernel(
    const float* __restrict__ nf, const float* __restrict__ W,
    const float* __restrict__ eemb, unsigned short* __restrict__ x_bf,
    unsigned short* __restrict__ Wt, unsigned short* __restrict__ em_bf,
    const int* __restrict__ eidx_tgt, int* __restrict__ counts,
    int n_nodes, int n_edges, int epb) {
  const int gid = blockIdx.x * 256 + threadIdx.x;
  const int stride = gridDim.x * 256;

  // ---- x cast: 8 floats -> 8 bf16 (uint4 store) per iteration ----
  const int total8 = n_nodes * (D / 8);
  const float4* nf4 = (const float4*)nf;
  uint4* xb4 = (uint4*)x_bf;
  for (int i = gid; i < total8; i += stride) {
    const float4 a = nf4[i * 2];
    const float4 c = nf4[i * 2 + 1];
    uint4 o;
    o.x = pkbf(a.x, a.y); o.y = pkbf(a.z, a.w);
    o.z = pkbf(c.x, c.y); o.w = pkbf(c.z, c.w);
    xb4[i] = o;
  }

  // ---- small tables + sentinel rows ----
  if (gid < D * D) Wt[gid] = f2bf(W[(gid & 127) * D + (gid >> 7)]);
  if (gid < 64 * D) em_bf[gid] = f2bf(eemb[gid]);
  if (gid < 64) ((unsigned int*)(x_bf + (size_t)n_nodes * D))[gid] = 0u;
  if (gid >= 64 && gid < 128)
    ((unsigned int*)(em_bf + 64 * D))[gid - 64] = 0u;

  // ---- fused edge-target histogram chunk ----
  const int ebase = blockIdx.x * epb;
  int eend = ebase + epb;
  if (eend > n_edges) eend = n_edges;
  for (int e = ebase + threadIdx.x; e < eend; e += 256)
    atomicAdd(&counts[eidx_tgt[e]], 1);
}

// ============================ scan =========================================
__global__ __launch_bounds__(256) void scan1_kernel(
    const int* __restrict__ counts, int* __restrict__ offsets,
    int* __restrict__ blockSums, int n) {
  __shared__ int lds[256];
  const int tid = threadIdx.x;
  const int base = blockIdx.x * 1024 + tid * 4;
  int v[4];
  #pragma unroll
  for (int k = 0; k < 4; ++k) v[k] = (base + k < n) ? counts[base + k] : 0;
  int s = v[0] + v[1] + v[2] + v[3];
  lds[tid] = s;
  for (int off = 1; off < 256; off <<= 1) {
    __syncthreads();
    int t = (tid >= off) ? lds[tid - off] : 0;
    __syncthreads();
    lds[tid] += t;
  }
  __syncthreads();
  int run = lds[tid] - s;
  #pragma unroll
  for (int k = 0; k < 4; ++k) {
    if (base + k < n) offsets[base + k] = run;
    run += v[k];
  }
  if (tid == 255) blockSums[blockIdx.x] = lds[255];
}

__global__ __launch_bounds__(256) void scan23_kernel(
    int* __restrict__ offsets, int* __restrict__ cursor,
    const int* __restrict__ blockSums, int nb, int n, int n_edges) {
  __shared__ int lds[256];
  const int tid = threadIdx.x;
  const int bid = blockIdx.x;
  lds[tid] = (tid < bid && tid < nb) ? blockSums[tid] : 0;
  __syncthreads();
  #pragma unroll
  for (int off = 128; off > 0; off >>= 1) {
    if (tid < off) lds[tid] += lds[tid + off];
    __syncthreads();
  }
  const int add = lds[0];
  const int base = bid * 1024 + tid * 4;
  #pragma unroll
  for (int k = 0; k < 4; ++k) {
    int i = base + k;
    if (i < n) {
      int o = offsets[i] + add;
      offsets[i] = o;
      cursor[i] = o;
    }
  }
  if (bid == 0 && tid == 0) offsets[n] = n_edges;
}

// ================== scatter: 4 edges/thread via int4 =======================
__global__ __launch_bounds__(256) void scatter_kernel(
    const int* __restrict__ eidx, const int* __restrict__ etype,
    int* __restrict__ cursor, unsigned int* __restrict__ packed, int n_edges) {
  const int e0 = (blockIdx.x * 256 + threadIdx.x) * 4;
  if (e0 + 3 < n_edges) {
    const int4 s4 = *(const int4*)&eidx[e0];
    const int4 t4 = *(const int4*)&eidx[n_edges + e0];
    const int4 y4 = *(const int4*)&etype[e0];
    int pos;
    pos = atomicAdd(&cursor[t4.x], 1);
    packed[pos] = (unsigned int)s4.x | ((unsigned int)y4.x << 17);
    pos = atomicAdd(&cursor[t4.y], 1);
    packed[pos] = (unsigned int)s4.y | ((unsigned int)y4.y << 17);
    pos = atomicAdd(&cursor[t4.z], 1);
    packed[pos] = (unsigned int)s4.z | ((unsigned int)y4.z << 17);
    pos = atomicAdd(&cursor[t4.w], 1);
    packed[pos] = (unsigned int)s4.w | ((unsigned int)y4.w << 17);
  } else {
    for (int e = e0; e < n_edges; ++e) {
      const int pos = atomicAdd(&cursor[eidx[n_edges + e]], 1);
      packed[pos] = (unsigned int)eidx[e] | ((unsigned int)etype[e] << 17);
    }
  }
}

// ====== fused aggregate + GEMM + ReLU: 512-thread block = 32 nodes =========
// out[n] = relu( (x[n] + Sum x[src]) @ W + (deg+1)*b + Sum emb[et] )
// Phase 1: each wave aggregates 4 nodes as 2 sequential pair-rounds
//   (half-wave = node, lane = 4 dims, 4-deep gather pipeline). Sequential
//   rounds smooth the Poisson imbalance before the single barrier.
// Phase 2: 32x128 output tile; wave w = cols [w*16,(w+1)*16), 2 node-tiles,
//   8 MFMAs; sums staged in XOR-swizzled LDS.
__global__ __launch_bounds__(512) void agg_gemm_kernel(
    const int* __restrict__ offsets, const unsigned int* __restrict__ packed,
    const uint2* __restrict__ e4, const uint2* __restrict__ x4,
    const unsigned short* __restrict__ Wt, const float* __restrict__ b,
    float* __restrict__ out, int n_nodes, int n_edges, unsigned int zero_p) {
  __shared__ uint2 sx_l[32 * 32];  // 32 nodes x 256B
  __shared__ uint2 se_l[32 * 32];
  __shared__ float deg_l[32];

  const int tid = threadIdx.x;
  const int w = tid >> 6;          // wave 0..7
  const int ln = tid & 63;
  const int half = ln >> 5;
  const int sl = ln & 31;
  const int nodeBase = blockIdx.x * 32;
  const int emax = n_edges - 1;

  // ---------------- phase 1: aggregate 2 rounds of node-pairs -------------
  #pragma unroll
  for (int r = 0; r < 2; ++r) {
    const int node32 = w * 4 + r * 2 + half;
    const int n = nodeBase + node32;   // always < n_nodes (100000 % 32 == 0)

    const uint2 sb = x4[(size_t)n * 32 + sl];
    float a0 = bflo(sb.x), a1 = bfhi(sb.x), a2 = bflo(sb.y), a3 = bfhi(sb.y);
    float c0 = 0.f, c1 = 0.f, c2 = 0.f, c3 = 0.f;
    float s0 = 0.f, s1 = 0.f, s2 = 0.f, s3 = 0.f;
    float u0 = 0.f, u1 = 0.f, u2 = 0.f, u3 = 0.f;

    int j = offsets[n];
    const int end = offsets[n + 1];
    const float degp1 = (float)(end - j) + 1.0f;
    int trips = (end - j + 3) >> 2;
    int to = __shfl_xor(trips, 32);
    const int T = trips > to ? trips : to;

    for (int t = 0; t < T; ++t, j += 4) {
      const int j1 = j + 1, j2 = j + 2, j3 = j + 3;
      unsigned int p0 = packed[j  <= emax ? j  : emax];
      unsigned int p1 = packed[j1 <= emax ? j1 : emax];
      unsigned int p2 = packed[j2 <= emax ? j2 : emax];
      unsigned int p3 = packed[j3 <= emax ? j3 : emax];
      p0 = (j  < end) ? p0 : zero_p;
      p1 = (j1 < end) ? p1 : zero_p;
      p2 = (j2 < end) ? p2 : zero_p;
      p3 = (j3 < end) ? p3 : zero_p;
      const uint2 g0 = x4[(size_t)(p0 & 0x1FFFFu) * 32 + sl];
      const uint2 g1 = x4[(size_t)(p1 & 0x1FFFFu) * 32 + sl];
      const uint2 g2 = x4[(size_t)(p2 & 0x1FFFFu) * 32 + sl];
      const uint2 g3 = x4[(size_t)(p3 & 0x1FFFFu) * 32 + sl];
      const uint2 e0 = e4[(p0 >> 17) * 32 + sl];
      const uint2 e1 = e4[(p1 >> 17) * 32 + sl];
      const uint2 e2 = e4[(p2 >> 17) * 32 + sl];
      const uint2 e3 = e4[(p3 >> 17) * 32 + sl];
      a0 += bflo(g0.x); a1 += bfhi(g0.x); a2 += bflo(g0.y); a3 += bfhi(g0.y);
      s0 += bflo(e0.x); s1 += bfhi(e0.x); s2 += bflo(e0.y); s3 += bfhi(e0.y);
      c0 += bflo(g1.x); c1 += bfhi(g1.x); c2 += bflo(g1.y); c3 += bfhi(g1.y);
      u0 += bflo(e1.x); u1 += bfhi(e1.x); u2 += bflo(e1.y); u3 += bfhi(e1.y);
      a0 += bflo(g2.x); a1 += bfhi(g2.x); a2 += bflo(g2.y); a3 += bfhi(g2.y);
      s0 += bflo(e2.x); s1 += bfhi(e2.x); s2 += bflo(e2.y); s3 += bfhi(e2.y);
      c0 += bflo(g3.x); c1 += bfhi(g3.x); c2 += bflo(g3.y); c3 += bfhi(g3.y);
      u0 += bflo(e3.x); u1 += bfhi(e3.x); u2 += bflo(e3.y); u3 += bfhi(e3.y);
    }

    const int byte = (node32 * 256 + sl * 8) ^ ((node32 & 7) << 4);
    uint2 vx, ve;
    vx.x = pkbf(a0 + c0, a1 + c1);
    vx.y = pkbf(a2 + c2, a3 + c3);
    ve.x = pkbf(s0 + u0, s1 + u1);
    ve.y = pkbf(s2 + u2, s3 + u3);
    *(uint2*)((char*)sx_l + byte) = vx;
    *(uint2*)((char*)se_l + byte) = ve;
    if (sl == 0) deg_l[node32] = degp1;
  }
  __syncthreads();

  // ---------------- phase 2: 32-node x 128-col GEMM tile -------------------
  const int m = ln & 15;   // node within 16-tile / D col group
  const int q = ln >> 4;   // k-quarter / D row-quarter

  short8v av[4];
  #pragma unroll
  for (int kc = 0; kc < 4; ++kc)
    av[kc] = *(const short8v*)&Wt[(w * 16 + m) * D + kc * 32 + q * 8];

  float4v acc[2] = {};
  #pragma unroll
  for (int t = 0; t < 2; ++t) {
    const int row = t * 16 + m;
    const int sw = (row & 7) << 4;
    #pragma unroll
    for (int kc = 0; kc < 4; ++kc) {
      const int bbyte = (row * 256 + kc * 64 + q * 16) ^ sw;
      const short8v bv = *(const short8v*)((const char*)sx_l + bbyte);
      acc[t] = __builtin_amdgcn_mfma_f32_16x16x32_bf16(av[kc], bv, acc[t],
                                                       0, 0, 0);
    }
  }

  // epilogue: + (deg+1)*b + se, ReLU, float4 store
  const int col0 = w * 16 + q * 4;
  const float4 bv = *(const float4*)&b[col0];
  #pragma unroll
  for (int t = 0; t < 2; ++t) {
    const int row = t * 16 + m;
    const int sbyte = (row * 256 + col0 * 2) ^ ((row & 7) << 4);
    const uint2 sev = *(const uint2*)((const char*)se_l + sbyte);
    const float dp1 = deg_l[row];
    float4 rr;
    rr.x = fmaxf(acc[t][0] + bv.x * dp1 + bflo(sev.x), 0.f);
    rr.y = fmaxf(acc[t][1] + bv.y * dp1 + bfhi(sev.x), 0.f);
    rr.z = fmaxf(acc[t][2] + bv.z * dp1 + bflo(sev.y), 0.f);
    rr.w = fmaxf(acc[t][3] + bv.w * dp1 + bfhi(sev.y), 0.f);
    *(float4*)&out[(size_t)(nodeBase + row) * D + col0] = rr;
  }
}

// ===========================================================================
extern "C" void kernel_launch(void* const* d_in, const int* in_sizes, int n_in,
                              void* d_out, int out_size, void* d_ws,
                              size_t ws_size, hipStream_t stream) {
  const float* nf   = (const float*)d_in[0];  // (N, 128) f32
  const int*   eidx = (const int*)d_in[1];    // (2, E) int
  const int*   etyp = (const int*)d_in[2];    // (E,) int
  const float* eemb = (const float*)d_in[3];  // (64, 128) f32
  const float* W    = (const float*)d_in[4];  // (128, 128) f32
  const float* b    = (const float*)d_in[5];  // (128,) f32

  const int n_nodes = in_sizes[0] / D;  // 100000
  const int n_edges = in_sizes[2];      // 625000

  float* out = (float*)d_out;

  // workspace layout (~29.5 MB); 16B alignment maintained
  char* base = (char*)d_ws;
  unsigned short* Wt = (unsigned short*)base;                  // 32 KB
  unsigned short* em_bf = (unsigned short*)(base + 32768);     // 65 rows
  unsigned short* x_bf = (unsigned short*)(base + 65536);      // (N+1)*128 bf16
  char* tail = base + 65536 + (size_t)(n_nodes + 1) * D * 2;
  int* counts = (int*)tail;
  int* offsets = counts + n_nodes;
  int* cursor = offsets + (n_nodes + 1);
  int* blockSums = cursor + n_nodes;
  unsigned int* packed = (unsigned int*)(blockSums + 1024);    // E uints

  const int nb = (n_nodes + 1023) / 1024;   // 98 scan blocks (<=256)
  const int prepBlocks = 2048;
  const int epb = (n_edges + prepBlocks - 1) / prepBlocks;  // ~306

  // 0) zero counts (must precede fused hist in prep)
  (void)hipMemsetAsync(counts, 0, (size_t)n_nodes * 4, stream);

  // 1) prep: x->bf16 cast, Wt/em tables, sentinels, fused histogram
  prep_kernel<<<prepBlocks, 256, 0, stream>>>(nf, W, eemb, x_bf, Wt, em_bf,
                                              eidx + n_edges, counts,
                                              n_nodes, n_edges, epb);

  // 2) scan (2 kernels)
  scan1_kernel<<<nb, 256, 0, stream>>>(counts, offsets, blockSums, n_nodes);
  scan23_kernel<<<nb, 256, 0, stream>>>(offsets, cursor, blockSums, nb,
                                        n_nodes, n_edges);

  // 3) scatter packed (src|etype) by target
  scatter_kernel<<<(n_edges + 1023) / 1024, 256, 0, stream>>>(
      eidx, etyp, cursor, packed, n_edges);

  // 4) fused aggregate + GEMM + ReLU (32 nodes / 512-thread block)
  const unsigned int zero_p = (unsigned int)n_nodes | (64u << 17);
  agg_gemm_kernel<<<n_nodes / 32, 512, 0, stream>>>(
      offsets, packed, (const uint2*)em_bf, (const uint2*)x_bf, Wt, b, out,
      n_nodes, n_edges, zero_p);
}